// Round 18
// baseline (67.014 us; speedup 1.0000x reference)
//
#include <hip/hip_runtime.h>
#include <hip/hip_bf16.h>

typedef __attribute__((ext_vector_type(8))) short short8;
typedef __attribute__((ext_vector_type(4))) float floatx4;

#define L2EPS 1e-12f

__device__ __forceinline__ unsigned short f2bf(float f) {
  union { float f; unsigned u; } c; c.f = f;
  unsigned u = c.u;
  unsigned r = (u + 0x7fffu + ((u >> 16) & 1u)) >> 16;  // RNE
  return (unsigned short)r;
}

__device__ __forceinline__ void gload_lds16(const void* g, void* l) {
  __builtin_amdgcn_global_load_lds(
      (const __attribute__((address_space(1))) unsigned int*)g,
      (__attribute__((address_space(3))) unsigned int*)l,
      16, 0, 0);
}

// ---------------------------------------------------------------------------
// Kernel 1: per-row inverse L2 norm of W (D rows of length N). One block/row.
// ---------------------------------------------------------------------------
__global__ __launch_bounds__(256) void wnorm_kernel(const float* __restrict__ W,
                                                    float* __restrict__ rnw, int N) {
  const int d = blockIdx.x;
  const float2* row2 = (const float2*)(W + (size_t)d * N);
  const int n2 = N >> 1;
  float s = 0.f;
  for (int i = threadIdx.x; i < n2; i += 256) {
    const float2 v = row2[i];
    s += v.x * v.x + v.y * v.y;
  }
  if (threadIdx.x == 0 && (N & 1)) {
    const float v = W[(size_t)d * N + (N - 1)];
    s += v * v;
  }
#pragma unroll
  for (int off = 32; off > 0; off >>= 1) s += __shfl_xor(s, off);
  __shared__ float red[4];
  if ((threadIdx.x & 63) == 0) red[threadIdx.x >> 6] = s;
  __syncthreads();
  if (threadIdx.x == 0)
    rnw[d] = rsqrtf(fmaxf(red[0] + red[1] + red[2] + red[3], L2EPS));
}

// ---------------------------------------------------------------------------
// Kernel 2 (fused dispatch): blocks [0,nxb): normalize x rows AND fold rnw.
// Blocks [nxb,...): transpose-cast BT[n][d] = bf16(W[d][n]), zero-padded.
// ---------------------------------------------------------------------------
__global__ __launch_bounds__(256) void prep_kernel(const float* __restrict__ x,
                                                   const float* __restrict__ W,
                                                   const float* __restrict__ rnw,
                                                   unsigned short* __restrict__ xb,
                                                   unsigned short* __restrict__ BT,
                                                   int N, int nxb, int nwx) {
  const int bid = blockIdx.x;
  if (bid < nxb) {
    const int lane = threadIdx.x & 63;
    const int wave = threadIdx.x >> 6;
    const int row  = bid * 4 + wave;
    const float4* xr = (const float4*)(x + (size_t)row * 512);
    const float4 v0 = xr[lane * 2];
    const float4 v1 = xr[lane * 2 + 1];
    float s = v0.x*v0.x + v0.y*v0.y + v0.z*v0.z + v0.w*v0.w
            + v1.x*v1.x + v1.y*v1.y + v1.z*v1.z + v1.w*v1.w;
#pragma unroll
    for (int off = 32; off > 0; off >>= 1) s += __shfl_xor(s, off);
    const float r = rsqrtf(fmaxf(s, L2EPS));
    const float4 w0 = ((const float4*)rnw)[lane * 2];
    const float4 w1 = ((const float4*)rnw)[lane * 2 + 1];
    short8 o;
    o[0] = (short)f2bf(v0.x * r * w0.x); o[1] = (short)f2bf(v0.y * r * w0.y);
    o[2] = (short)f2bf(v0.z * r * w0.z); o[3] = (short)f2bf(v0.w * r * w0.w);
    o[4] = (short)f2bf(v1.x * r * w1.x); o[5] = (short)f2bf(v1.y * r * w1.y);
    o[6] = (short)f2bf(v1.z * r * w1.z); o[7] = (short)f2bf(v1.w * r * w1.w);
    *(short8*)(xb + (size_t)row * 512 + lane * 8) = o;
  } else {
    __shared__ unsigned short tile[32][33];
    const int wb = bid - nxb;
    const int n0 = (wb % nwx) * 32;
    const int d0 = (wb / nwx) * 32;
    const int tx = threadIdx.x & 31;
    const int ty = threadIdx.x >> 5;  // 0..7
#pragma unroll
    for (int i = 0; i < 4; ++i) {
      const int dl = ty + i * 8;
      const int n = n0 + tx;
      float v = 0.f;
      if (n < N) v = W[(size_t)(d0 + dl) * N + n];
      tile[tx][dl] = f2bf(v);
    }
    __syncthreads();
#pragma unroll
    for (int i = 0; i < 4; ++i) {
      const int nl = ty + i * 8;
      BT[(size_t)(n0 + nl) * 512 + d0 + tx] = tile[nl][tx];
    }
  }
}

// ---------------------------------------------------------------------------
// Kernel 3: ONE-PASS GEMM (r16 geometry) + counted-vmcnt 4-deep pipeline.
// Tile 256x384, grid 16x16 = 256 blocks = 1/CU, one pass, zero tail.
// 8 waves (2M x 4N, wave 128x96, acc 8x6). BK=32 -> 16 K-tiles; LDS
// 4 buffers x (A 16KB + B 24KB) = 160KB. 3-ahead staging (5 instrs/tile),
// steady-state s_waitcnt vmcnt(10) -- loads stay in flight across barriers;
// drains only at t=13/14 (5,0). Hazards: STAGE(t+3) overwrites buf (t-1)&3
// whose ds_reads retired before barrier t-1; vmcnt(10) at end of t => tile
// t+1 landed (FIFO). Chunk-XOR swizzle (r3-measured-0-conflict family for
// 64B rows): staging source chunk^((row>>1)&3), reads q4^((ln15>>1)&3).
// Epilogue + XCD strips identical to r16.
// ---------------------------------------------------------------------------
__global__ __launch_bounds__(512, 2) void gemm_kernel(
    const unsigned short* __restrict__ A,   // (4096,512) bf16 (xn * rnw)
    const unsigned short* __restrict__ BT,  // (6144,512) bf16 (W^T, padded)
    float* __restrict__ C,                  // (4096,N) f32
    int N) {
  __shared__ unsigned short As[4][256 * 32];   // 4 x 16 KB
  __shared__ unsigned short Bs[4][384 * 32];   // 4 x 24 KB

  const int tid = threadIdx.x;
  const int l   = tid & 63;
  const int w   = tid >> 6;   // 0..7
  const int wr  = w >> 2;     // 0..1  (M half)
  const int wc  = w & 3;      // 0..3  (N quarter)

  // XCD mapping: 256 blocks = 8 XCDs x 32; XCD c owns a 2bx x 16by strip.
  const int bid = blockIdx.x;
  const int c   = bid & 7;
  const int i   = bid >> 3;                 // 0..31
  const int bx  = c * 2 + (i >> 4);         // 0..15
  const int by  = i & 15;                   // 0..15
  const int row0 = by * 256;
  const int col0 = bx * 384;

  floatx4 acc[8][6];
#pragma unroll
  for (int m = 0; m < 8; ++m)
#pragma unroll
    for (int n = 0; n < 6; ++n)
      acc[m][n] = (floatx4){0.f, 0.f, 0.f, 0.f};

  // staging: one instr = 512 thr x 16B = 8KB = 128 rows of 64B.
  // A: 2 instrs (256 rows), B: 3 instrs (384 rows). LDS dest linear
  // (tid*16B); SOURCE chunk pre-swizzled: chunk_g = (tid&3) ^ ((srow>>1)&3),
  // srow = tid>>2 (row bases are multiples of 128 -> (row>>1)&3 invariant).
  const int srow = tid >> 2;                               // 0..127
  const int sch  = ((tid & 3) ^ ((tid >> 3) & 3)) * 8;     // elems
  const unsigned short* Ap = A  + (size_t)(row0 + srow) * 512 + sch;
  const unsigned short* Bp = BT + (size_t)(col0 + srow) * 512 + sch;
  const int lo = tid * 8;                                  // LDS elems

#define STAGE(t_) do { \
    _Pragma("unroll") \
    for (int ii = 0; ii < 2; ++ii) \
      gload_lds16(Ap + (size_t)(ii * 128) * 512 + (t_) * 32, &As[(t_) & 3][ii * 4096 + lo]); \
    _Pragma("unroll") \
    for (int ii = 0; ii < 3; ++ii) \
      gload_lds16(Bp + (size_t)(ii * 128) * 512 + (t_) * 32, &Bs[(t_) & 3][ii * 4096 + lo]); \
  } while (0)

  // frag-read geometry (64B rows): elem = row*32 + (q4^((row>>1)&3))*8,
  // (row>>1)&3 = (ln15>>1)&3 (row bases are multiples of 16). 0 conflicts
  // (r3-measured, identical family).
  const int ln15 = l & 15;
  const int q4   = l >> 4;
  const int cs   = (q4 ^ ((ln15 >> 1) & 3)) * 8;
  const int aoff = (wr * 128 + ln15) * 32 + cs;   // + m*512
  const int boff = (wc * 96 + ln15) * 32 + cs;    // + n*512

  // prologue: 3 tiles in flight (15 loads); wait tile0 (leave 10).
  STAGE(0); STAGE(1); STAGE(2);
  asm volatile("s_waitcnt vmcnt(10)" ::: "memory");
  __syncthreads();

#pragma unroll
  for (int t = 0; t < 16; ++t) {
    const int b = t & 3;
    if (t + 3 < 16) STAGE(t + 3);   // overwrites buf (t-1)&3: reads retired
    short8 af[8], bf[6];
#pragma unroll
    for (int m = 0; m < 8; ++m) af[m] = *(const short8*)&As[b][aoff + m * 512];
#pragma unroll
    for (int n = 0; n < 6; ++n) bf[n] = *(const short8*)&Bs[b][boff + n * 512];
#pragma unroll
    for (int m = 0; m < 8; ++m)
#pragma unroll
      for (int n = 0; n < 6; ++n)
        acc[m][n] = __builtin_amdgcn_mfma_f32_16x16x32_bf16(af[m], bf[n], acc[m][n], 0, 0, 0);
    // counted publish of tile t+1 (never drains until the tail)
    if (t < 13)       asm volatile("s_waitcnt vmcnt(10)" ::: "memory");
    else if (t == 13) asm volatile("s_waitcnt vmcnt(5)"  ::: "memory");
    else if (t == 14) asm volatile("s_waitcnt vmcnt(0)"  ::: "memory");
    if (t < 15) __syncthreads();
  }
#undef STAGE

  // epilogue: C/D layout col=lane&15, row=(lane>>4)*4+r; n-inner scalar.
  const int rb = row0 + wr * 128 + q4 * 4;
  const int cb = col0 + wc * 96 + ln15;
#pragma unroll
  for (int m = 0; m < 8; ++m) {
#pragma unroll
    for (int r = 0; r < 4; ++r) {
      const size_t o = (size_t)(rb + m * 16 + r) * N + cb;
#pragma unroll
      for (int n = 0; n < 6; ++n) {
        if (cb + n * 16 < N) C[o + n * 16] = acc[m][n][r];
      }
    }
  }
}

// ---------------------------------------------------------------------------
extern "C" void kernel_launch(void* const* d_in, const int* in_sizes, int n_in,
                              void* d_out, int out_size, void* d_ws, size_t ws_size,
                              hipStream_t stream) {
  const float* x = (const float*)d_in[0];
  const float* W = (const float*)d_in[1];
  float* out = (float*)d_out;

  const int D = 512;
  const int B = in_sizes[0] / D;            // 4096
  const int N = in_sizes[1] / D;            // 5994
  const int Npad = 6144;                    // 16 x 384

  char* ws = (char*)d_ws;
  unsigned short* xb  = (unsigned short*)ws;                          // B*D*2
  unsigned short* BTb = (unsigned short*)(ws + (size_t)B * D * 2);    // Npad*D*2
  float* rnw = (float*)(ws + (size_t)B * D * 2 + (size_t)Npad * D * 2);

  const int nxb = B / 4;           // 1024 xnorm blocks
  const int nwx = Npad / 32;       // 192 wtrans tiles per d-stripe
  const int nwb = nwx * (D / 32);  // 3072 wtrans blocks

  wnorm_kernel<<<D, 256, 0, stream>>>(W, rnw, N);
  prep_kernel<<<nxb + nwb, 256, 0, stream>>>(x, W, rnw, xb, BTb, N, nxb, nwx);
  gemm_kernel<<<(B / 256) * (Npad / 384), 512, 0, stream>>>(xb, BTb, out, N);
}

// Round 19
// 56.296 us; speedup vs baseline: 1.1904x; 1.1904x over previous
//
#include <hip/hip_runtime.h>
#include <hip/hip_bf16.h>

typedef __attribute__((ext_vector_type(8))) short short8;
typedef __attribute__((ext_vector_type(4))) float floatx4;

#define L2EPS 1e-12f

__device__ __forceinline__ unsigned short f2bf(float f) {
  union { float f; unsigned u; } c; c.f = f;
  unsigned u = c.u;
  unsigned r = (u + 0x7fffu + ((u >> 16) & 1u)) >> 16;  // RNE
  return (unsigned short)r;
}

__device__ __forceinline__ void gload_lds16(const void* g, void* l) {
  __builtin_amdgcn_global_load_lds(
      (const __attribute__((address_space(1))) unsigned int*)g,
      (__attribute__((address_space(3))) unsigned int*)l,
      16, 0, 0);
}

// ---------------------------------------------------------------------------
// Kernel 1 (fused, independent halves — r13-proven):
//   blocks [0, nxb):      xnorm: xb[row] = bf16(x[row] * rsqrt(sum x^2))
//   blocks [nxb, nxb+D):  wnorm: rnw[d] = rsqrt(max(sum_n W[d,n]^2, eps))
// rnw is folded into BT in kernel 2, so xnorm does NOT depend on wnorm and
// both halves stream concurrently in one dispatch.
// ---------------------------------------------------------------------------
__global__ __launch_bounds__(256) void prep1_kernel(const float* __restrict__ x,
                                                    const float* __restrict__ W,
                                                    unsigned short* __restrict__ xb,
                                                    float* __restrict__ rnw,
                                                    int N, int nxb) {
  const int bid = blockIdx.x;
  if (bid < nxb) {
    const int lane = threadIdx.x & 63;
    const int wave = threadIdx.x >> 6;
    const int row  = bid * 4 + wave;
    const float4* xr = (const float4*)(x + (size_t)row * 512);
    const float4 v0 = xr[lane * 2];
    const float4 v1 = xr[lane * 2 + 1];
    float s = v0.x*v0.x + v0.y*v0.y + v0.z*v0.z + v0.w*v0.w
            + v1.x*v1.x + v1.y*v1.y + v1.z*v1.z + v1.w*v1.w;
#pragma unroll
    for (int off = 32; off > 0; off >>= 1) s += __shfl_xor(s, off);
    const float r = rsqrtf(fmaxf(s, L2EPS));
    short8 o;
    o[0] = (short)f2bf(v0.x * r); o[1] = (short)f2bf(v0.y * r);
    o[2] = (short)f2bf(v0.z * r); o[3] = (short)f2bf(v0.w * r);
    o[4] = (short)f2bf(v1.x * r); o[5] = (short)f2bf(v1.y * r);
    o[6] = (short)f2bf(v1.z * r); o[7] = (short)f2bf(v1.w * r);
    *(short8*)(xb + (size_t)row * 512 + lane * 8) = o;
  } else {
    const int d = bid - nxb;
    const float2* row2 = (const float2*)(W + (size_t)d * N);
    const int n2 = N >> 1;
    float s = 0.f;
    for (int i = threadIdx.x; i < n2; i += 256) {
      const float2 v = row2[i];
      s += v.x * v.x + v.y * v.y;
    }
    if (threadIdx.x == 0 && (N & 1)) {
      const float v = W[(size_t)d * N + (N - 1)];
      s += v * v;
    }
#pragma unroll
    for (int off = 32; off > 0; off >>= 1) s += __shfl_xor(s, off);
    __shared__ float red[4];
    if ((threadIdx.x & 63) == 0) red[threadIdx.x >> 6] = s;
    __syncthreads();
    if (threadIdx.x == 0)
      rnw[d] = rsqrtf(fmaxf(red[0] + red[1] + red[2] + red[3], L2EPS));
  }
}

// ---------------------------------------------------------------------------
// Kernel 2: BT[n][d] = bf16(W[d][n] * rnw[d]), n in [0, Npad) zero-padded.
// W is L3-warm from kernel 1's wnorm pass.
// ---------------------------------------------------------------------------
__global__ __launch_bounds__(256) void wtrans_kernel(const float* __restrict__ W,
                                                     const float* __restrict__ rnw,
                                                     unsigned short* __restrict__ BT,
                                                     int N, int nwx) {
  __shared__ unsigned short tile[32][33];
  const int n0 = (blockIdx.x % nwx) * 32;
  const int d0 = (blockIdx.x / nwx) * 32;
  const int tx = threadIdx.x & 31;
  const int ty = threadIdx.x >> 5;  // 0..7
#pragma unroll
  for (int i = 0; i < 4; ++i) {
    const int dl = ty + i * 8;
    const int d = d0 + dl;
    const int n = n0 + tx;
    float v = 0.f;
    if (n < N) v = W[(size_t)d * N + n] * rnw[d];
    tile[tx][dl] = f2bf(v);
  }
  __syncthreads();
#pragma unroll
  for (int i = 0; i < 4; ++i) {
    const int nl = ty + i * 8;
    BT[(size_t)(n0 + nl) * 512 + d0 + tx] = tile[nl][tx];
  }
}

// ---------------------------------------------------------------------------
// Kernel 3: EXACTLY-ONE-PASS GEMM — r16 champion, byte-identical.
// Tile 256x384, grid 16x16 = 256 blocks = 1 block/CU, one pass, zero tail.
// 8 waves (2M x 4N, wave = 128x96, acc 8x6). BK=64, double-buffered LDS
// (2 x (A 32KB + B 48KB) = exactly 160KB). Per K-tile: stage next (10
// instrs) -> compute (96 MFMA/wave) -> vmcnt(0) + one barrier. Chunk-XOR
// swizzle both sides (r3-measured 0 conflicts), source pre-swizzled
// (rule #21). n-inner scalar epilogue (measured near-ideal WRITE ~97MB).
// A carries pure xn; BT carries rnw (exactly one factor holds the W-norm).
// ---------------------------------------------------------------------------
__global__ __launch_bounds__(512, 2) void gemm_kernel(
    const unsigned short* __restrict__ A,   // (4096,512) bf16 (xn)
    const unsigned short* __restrict__ BT,  // (6144,512) bf16 (W^T * rnw, padded)
    float* __restrict__ C,                  // (4096,N) f32
    int N) {
  __shared__ unsigned short As[2][256 * 64];   // 2 x 32 KB
  __shared__ unsigned short Bs[2][384 * 64];   // 2 x 48 KB

  const int tid = threadIdx.x;
  const int l   = tid & 63;
  const int w   = tid >> 6;   // 0..7
  const int wr  = w >> 2;     // 0..1  (M half)
  const int wc  = w & 3;      // 0..3  (N quarter)

  // XCD mapping: 256 blocks = 8 XCDs x 32; XCD c owns a 2bx x 16by strip.
  const int bid = blockIdx.x;
  const int c   = bid & 7;
  const int i   = bid >> 3;                 // 0..31
  const int bx  = c * 2 + (i >> 4);         // 0..15
  const int by  = i & 15;                   // 0..15
  const int row0 = by * 256;
  const int col0 = bx * 384;

  floatx4 acc[8][6];
#pragma unroll
  for (int m = 0; m < 8; ++m)
#pragma unroll
    for (int n = 0; n < 6; ++n)
      acc[m][n] = (floatx4){0.f, 0.f, 0.f, 0.f};

  // staging: one instr = 512 thr x 16B = 8KB = 64 rows of 128B.
  // A: 4 instrs, B: 6 instrs. LDS dest linear; SOURCE chunk pre-swizzled:
  // chunk_g = (tid&7) ^ (srow&7) (instr row-bases are multiples of 64).
  const int srow = tid >> 3;                               // 0..63
  const int sch  = ((tid & 7) ^ (srow & 7)) * 8;           // elems
  const unsigned short* Ap = A  + (size_t)(row0 + srow) * 512 + sch;
  const unsigned short* Bp = BT + (size_t)(col0 + srow) * 512 + sch;
  const int lo = tid * 8;                                  // LDS elems

#define STAGE(t_) do { \
    _Pragma("unroll") \
    for (int ii = 0; ii < 4; ++ii) \
      gload_lds16(Ap + (size_t)(ii * 64) * 512 + (t_) * 64, &As[(t_) & 1][ii * 4096 + lo]); \
    _Pragma("unroll") \
    for (int ii = 0; ii < 6; ++ii) \
      gload_lds16(Bp + (size_t)(ii * 64) * 512 + (t_) * 64, &Bs[(t_) & 1][ii * 4096 + lo]); \
  } while (0)

  // frag-read geometry: elem = row*64 + ((ks*4+q4)^(row&7))*8; consecutive
  // 8-lane groups cover 8 distinct 16B bank-groups (0 conflicts, r3-measured).
  const int ln15 = l & 15;
  const int q4   = l >> 4;
  const int e7   = ln15 & 7;
  const int cs0  = ((q4) ^ e7) * 8;
  const int cs1  = ((4 + q4) ^ e7) * 8;
  const int aoff = (wr * 128 + ln15) * 64;  // + m*1024
  const int boff = (wc * 96 + ln15) * 64;   // + n*1024

  // prologue: tile 0 staged, landed, published.
  STAGE(0);
  asm volatile("s_waitcnt vmcnt(0)" ::: "memory");
  __syncthreads();

#pragma unroll
  for (int t = 0; t < 8; ++t) {
    const int b = t & 1;
    if (t + 1 < 8) STAGE(t + 1);   // into other buffer; flies during compute
#pragma unroll
    for (int ks = 0; ks < 2; ++ks) {
      const int cs = ks ? cs1 : cs0;
      short8 af[8], bf[6];
#pragma unroll
      for (int m = 0; m < 8; ++m) af[m] = *(const short8*)&As[b][aoff + m * 1024 + cs];
#pragma unroll
      for (int n = 0; n < 6; ++n) bf[n] = *(const short8*)&Bs[b][boff + n * 1024 + cs];
#pragma unroll
      for (int m = 0; m < 8; ++m)
#pragma unroll
        for (int n = 0; n < 6; ++n)
          acc[m][n] = __builtin_amdgcn_mfma_f32_16x16x32_bf16(af[m], bf[n], acc[m][n], 0, 0, 0);
    }
    if (t + 1 < 8) {
      asm volatile("s_waitcnt vmcnt(0)" ::: "memory");  // tile t+1 landed
      __syncthreads();                                  // publish + reads of buf b done
    }
  }
#undef STAGE

  // epilogue: C/D layout col=lane&15, row=(lane>>4)*4+r; n-inner scalar.
  const int rb = row0 + wr * 128 + q4 * 4;
  const int cb = col0 + wc * 96 + ln15;
#pragma unroll
  for (int m = 0; m < 8; ++m) {
#pragma unroll
    for (int r = 0; r < 4; ++r) {
      const size_t o = (size_t)(rb + m * 16 + r) * N + cb;
#pragma unroll
      for (int n = 0; n < 6; ++n) {
        if (cb + n * 16 < N) C[o + n * 16] = acc[m][n][r];
      }
    }
  }
}

// ---------------------------------------------------------------------------
extern "C" void kernel_launch(void* const* d_in, const int* in_sizes, int n_in,
                              void* d_out, int out_size, void* d_ws, size_t ws_size,
                              hipStream_t stream) {
  const float* x = (const float*)d_in[0];
  const float* W = (const float*)d_in[1];
  float* out = (float*)d_out;

  const int D = 512;
  const int B = in_sizes[0] / D;            // 4096
  const int N = in_sizes[1] / D;            // 5994
  const int Npad = 6144;                    // 16 x 384

  char* ws = (char*)d_ws;
  unsigned short* xb  = (unsigned short*)ws;                          // B*D*2
  unsigned short* BTb = (unsigned short*)(ws + (size_t)B * D * 2);    // Npad*D*2
  float* rnw = (float*)(ws + (size_t)B * D * 2 + (size_t)Npad * D * 2);

  const int nxb = B / 4;           // 1024 xnorm blocks
  const int nwx = Npad / 32;       // 192 wtrans tiles per d-stripe

  prep1_kernel<<<nxb + D, 256, 0, stream>>>(x, W, xb, rnw, N, nxb);
  wtrans_kernel<<<nwx * (D / 32), 256, 0, stream>>>(W, rnw, BTb, N, nwx);
  gemm_kernel<<<(B / 256) * (Npad / 384), 512, 0, stream>>>(xb, BTb, out, N);
}

// Round 20
// 54.725 us; speedup vs baseline: 1.2246x; 1.0287x over previous
//
#include <hip/hip_runtime.h>
#include <hip/hip_bf16.h>

typedef __attribute__((ext_vector_type(8))) short short8;
typedef __attribute__((ext_vector_type(4))) float floatx4;

#define L2EPS 1e-12f

__device__ __forceinline__ unsigned short f2bf(float f) {
  union { float f; unsigned u; } c; c.f = f;
  unsigned u = c.u;
  unsigned r = (u + 0x7fffu + ((u >> 16) & 1u)) >> 16;  // RNE
  return (unsigned short)r;
}

__device__ __forceinline__ void gload_lds16(const void* g, void* l) {
  __builtin_amdgcn_global_load_lds(
      (const __attribute__((address_space(1))) unsigned int*)g,
      (__attribute__((address_space(3))) unsigned int*)l,
      16, 0, 0);
}

// ---------------------------------------------------------------------------
// Kernel 1: per-row inverse L2 norm of W (D rows of length N). One block/row.
// ---------------------------------------------------------------------------
__global__ __launch_bounds__(256) void wnorm_kernel(const float* __restrict__ W,
                                                    float* __restrict__ rnw, int N) {
  const int d = blockIdx.x;
  const float2* row2 = (const float2*)(W + (size_t)d * N);
  const int n2 = N >> 1;
  float s = 0.f;
  for (int i = threadIdx.x; i < n2; i += 256) {
    const float2 v = row2[i];
    s += v.x * v.x + v.y * v.y;
  }
  if (threadIdx.x == 0 && (N & 1)) {
    const float v = W[(size_t)d * N + (N - 1)];
    s += v * v;
  }
#pragma unroll
  for (int off = 32; off > 0; off >>= 1) s += __shfl_xor(s, off);
  __shared__ float red[4];
  if ((threadIdx.x & 63) == 0) red[threadIdx.x >> 6] = s;
  __syncthreads();
  if (threadIdx.x == 0)
    rnw[d] = rsqrtf(fmaxf(red[0] + red[1] + red[2] + red[3], L2EPS));
}

// ---------------------------------------------------------------------------
// Kernel 2 (fused dispatch): blocks [0,nxb): normalize x rows AND fold rnw.
// Blocks [nxb,...): transpose-cast BT[n][d] = bf16(W[d][n]), zero-padded.
// ---------------------------------------------------------------------------
__global__ __launch_bounds__(256) void prep_kernel(const float* __restrict__ x,
                                                   const float* __restrict__ W,
                                                   const float* __restrict__ rnw,
                                                   unsigned short* __restrict__ xb,
                                                   unsigned short* __restrict__ BT,
                                                   int N, int nxb, int nwx) {
  const int bid = blockIdx.x;
  if (bid < nxb) {
    const int lane = threadIdx.x & 63;
    const int wave = threadIdx.x >> 6;
    const int row  = bid * 4 + wave;
    const float4* xr = (const float4*)(x + (size_t)row * 512);
    const float4 v0 = xr[lane * 2];
    const float4 v1 = xr[lane * 2 + 1];
    float s = v0.x*v0.x + v0.y*v0.y + v0.z*v0.z + v0.w*v0.w
            + v1.x*v1.x + v1.y*v1.y + v1.z*v1.z + v1.w*v1.w;
#pragma unroll
    for (int off = 32; off > 0; off >>= 1) s += __shfl_xor(s, off);
    const float r = rsqrtf(fmaxf(s, L2EPS));
    const float4 w0 = ((const float4*)rnw)[lane * 2];
    const float4 w1 = ((const float4*)rnw)[lane * 2 + 1];
    short8 o;
    o[0] = (short)f2bf(v0.x * r * w0.x); o[1] = (short)f2bf(v0.y * r * w0.y);
    o[2] = (short)f2bf(v0.z * r * w0.z); o[3] = (short)f2bf(v0.w * r * w0.w);
    o[4] = (short)f2bf(v1.x * r * w1.x); o[5] = (short)f2bf(v1.y * r * w1.y);
    o[6] = (short)f2bf(v1.z * r * w1.z); o[7] = (short)f2bf(v1.w * r * w1.w);
    *(short8*)(xb + (size_t)row * 512 + lane * 8) = o;
  } else {
    __shared__ unsigned short tile[32][33];
    const int wb = bid - nxb;
    const int n0 = (wb % nwx) * 32;
    const int d0 = (wb / nwx) * 32;
    const int tx = threadIdx.x & 31;
    const int ty = threadIdx.x >> 5;  // 0..7
#pragma unroll
    for (int i = 0; i < 4; ++i) {
      const int dl = ty + i * 8;
      const int n = n0 + tx;
      float v = 0.f;
      if (n < N) v = W[(size_t)(d0 + dl) * N + n];
      tile[tx][dl] = f2bf(v);
    }
    __syncthreads();
#pragma unroll
    for (int i = 0; i < 4; ++i) {
      const int nl = ty + i * 8;
      BT[(size_t)(n0 + nl) * 512 + d0 + tx] = tile[nl][tx];
    }
  }
}

// ---------------------------------------------------------------------------
// Kernel 3: EXACTLY-ONE-PASS GEMM (r16 champion). Tile 256x384, grid 16x16 =
// 256 blocks = 1 block/CU, one pass, zero tail: each CU pays ONE prologue +
// 8 drains + ONE epilogue for the entire GEMM. 8 waves (2M x 4N, wave =
// 128x96, acc 8x6 frags). BK=64, double-buffered LDS (2 x (A 32KB + B 48KB)
// = exactly 160KB). Per K-tile: stage next (10 instrs) -> compute current
// (96 MFMA/wave) -> vmcnt(0) + one barrier. Chunk-XOR swizzle both sides
// (r3-measured 0 conflicts); source pre-swizzled (rule #21). n-inner scalar
// epilogue (measured near-ideal WRITE ~97MB).
// ---------------------------------------------------------------------------
__global__ __launch_bounds__(512, 2) void gemm_kernel(
    const unsigned short* __restrict__ A,   // (4096,512) bf16 (xn * rnw)
    const unsigned short* __restrict__ BT,  // (6144,512) bf16 (W^T, padded)
    float* __restrict__ C,                  // (4096,N) f32
    int N) {
  __shared__ unsigned short As[2][256 * 64];   // 2 x 32 KB
  __shared__ unsigned short Bs[2][384 * 64];   // 2 x 48 KB

  const int tid = threadIdx.x;
  const int l   = tid & 63;
  const int w   = tid >> 6;   // 0..7
  const int wr  = w >> 2;     // 0..1  (M half)
  const int wc  = w & 3;      // 0..3  (N quarter)

  // XCD mapping: 256 blocks = 8 XCDs x 32; XCD c owns a 2bx x 16by strip
  // (B panels 2 x 384KB L2-resident; A via L3).
  const int bid = blockIdx.x;
  const int c   = bid & 7;
  const int i   = bid >> 3;                 // 0..31
  const int bx  = c * 2 + (i >> 4);         // 0..15
  const int by  = i & 15;                   // 0..15
  const int row0 = by * 256;
  const int col0 = bx * 384;

  floatx4 acc[8][6];
#pragma unroll
  for (int m = 0; m < 8; ++m)
#pragma unroll
    for (int n = 0; n < 6; ++n)
      acc[m][n] = (floatx4){0.f, 0.f, 0.f, 0.f};

  // staging: one instr = 512 thr x 16B = 8KB = 64 rows of 128B.
  // A: 4 instrs (256 rows), B: 6 instrs (384 rows). LDS dest linear
  // (tid*16B within instr); SOURCE chunk pre-swizzled:
  // chunk_g = (tid&7) ^ (srow&7); instr row-base is a multiple of 64 so
  // (row&7) == (srow&7) for all instrs.
  const int srow = tid >> 3;                               // 0..63
  const int sch  = ((tid & 7) ^ (srow & 7)) * 8;           // elems
  const unsigned short* Ap = A  + (size_t)(row0 + srow) * 512 + sch;
  const unsigned short* Bp = BT + (size_t)(col0 + srow) * 512 + sch;
  const int lo = tid * 8;                                  // LDS elems

#define STAGE(t_) do { \
    _Pragma("unroll") \
    for (int ii = 0; ii < 4; ++ii) \
      gload_lds16(Ap + (size_t)(ii * 64) * 512 + (t_) * 64, &As[(t_) & 1][ii * 4096 + lo]); \
    _Pragma("unroll") \
    for (int ii = 0; ii < 6; ++ii) \
      gload_lds16(Bp + (size_t)(ii * 64) * 512 + (t_) * 64, &Bs[(t_) & 1][ii * 4096 + lo]); \
  } while (0)

  // frag-read geometry: elem = row*64 + ((ks*4+q4)^(row&7))*8; consecutive
  // 8-lane groups cover 8 distinct 16B bank-groups (0 conflicts, r3-measured).
  const int ln15 = l & 15;
  const int q4   = l >> 4;
  const int e7   = ln15 & 7;
  const int cs0  = ((q4) ^ e7) * 8;
  const int cs1  = ((4 + q4) ^ e7) * 8;
  const int aoff = (wr * 128 + ln15) * 64;  // + m*1024
  const int boff = (wc * 96 + ln15) * 64;   // + n*1024

  // prologue: tile 0 staged, landed, published.
  STAGE(0);
  asm volatile("s_waitcnt vmcnt(0)" ::: "memory");
  __syncthreads();

#pragma unroll
  for (int t = 0; t < 8; ++t) {
    const int b = t & 1;
    if (t + 1 < 8) STAGE(t + 1);   // into other buffer; flies during compute
#pragma unroll
    for (int ks = 0; ks < 2; ++ks) {
      const int cs = ks ? cs1 : cs0;
      short8 af[8], bf[6];
#pragma unroll
      for (int m = 0; m < 8; ++m) af[m] = *(const short8*)&As[b][aoff + m * 1024 + cs];
#pragma unroll
      for (int n = 0; n < 6; ++n) bf[n] = *(const short8*)&Bs[b][boff + n * 1024 + cs];
#pragma unroll
      for (int m = 0; m < 8; ++m)
#pragma unroll
        for (int n = 0; n < 6; ++n)
          acc[m][n] = __builtin_amdgcn_mfma_f32_16x16x32_bf16(af[m], bf[n], acc[m][n], 0, 0, 0);
    }
    if (t + 1 < 8) {
      asm volatile("s_waitcnt vmcnt(0)" ::: "memory");  // tile t+1 landed
      __syncthreads();                                  // publish + reads of buf b done
    }
  }
#undef STAGE

  // epilogue: C/D layout col=lane&15, row=(lane>>4)*4+r; n-inner scalar.
  const int rb = row0 + wr * 128 + q4 * 4;
  const int cb = col0 + wc * 96 + ln15;
#pragma unroll
  for (int m = 0; m < 8; ++m) {
#pragma unroll
    for (int r = 0; r < 4; ++r) {
      const size_t o = (size_t)(rb + m * 16 + r) * N + cb;
#pragma unroll
      for (int n = 0; n < 6; ++n) {
        if (cb + n * 16 < N) C[o + n * 16] = acc[m][n][r];
      }
    }
  }
}

// ---------------------------------------------------------------------------
extern "C" void kernel_launch(void* const* d_in, const int* in_sizes, int n_in,
                              void* d_out, int out_size, void* d_ws, size_t ws_size,
                              hipStream_t stream) {
  const float* x = (const float*)d_in[0];
  const float* W = (const float*)d_in[1];
  float* out = (float*)d_out;

  const int D = 512;
  const int B = in_sizes[0] / D;            // 4096
  const int N = in_sizes[1] / D;            // 5994
  const int Npad = 6144;                    // 16 x 384

  char* ws = (char*)d_ws;
  unsigned short* xb  = (unsigned short*)ws;                          // B*D*2
  unsigned short* BTb = (unsigned short*)(ws + (size_t)B * D * 2);    // Npad*D*2
  float* rnw = (float*)(ws + (size_t)B * D * 2 + (size_t)Npad * D * 2);

  const int nxb = B / 4;           // 1024 xnorm blocks
  const int nwx = Npad / 32;       // 192 wtrans tiles per d-stripe
  const int nwb = nwx * (D / 32);  // 3072 wtrans blocks

  wnorm_kernel<<<D, 256, 0, stream>>>(W, rnw, N);
  prep_kernel<<<nxb + nwb, 256, 0, stream>>>(x, W, rnw, xb, BTb, N, nxb, nwx);
  gemm_kernel<<<(B / 256) * (Npad / 384), 512, 0, stream>>>(xb, BTb, out, N);
}

// Round 21
// 54.700 us; speedup vs baseline: 1.2251x; 1.0005x over previous
//
#include <hip/hip_runtime.h>
#include <hip/hip_bf16.h>

typedef __attribute__((ext_vector_type(8))) short short8;
typedef __attribute__((ext_vector_type(4))) float floatx4;

#define L2EPS 1e-12f

__device__ __forceinline__ unsigned short f2bf(float f) {
  union { float f; unsigned u; } c; c.f = f;
  unsigned u = c.u;
  unsigned r = (u + 0x7fffu + ((u >> 16) & 1u)) >> 16;  // RNE
  return (unsigned short)r;
}

__device__ __forceinline__ void gload_lds16(const void* g, void* l) {
  __builtin_amdgcn_global_load_lds(
      (const __attribute__((address_space(1))) unsigned int*)g,
      (__attribute__((address_space(3))) unsigned int*)l,
      16, 0, 0);
}

// ---------------------------------------------------------------------------
// Kernel 1: per-row inverse L2 norm of W (D rows of length N). One block/row.
// ---------------------------------------------------------------------------
__global__ __launch_bounds__(256) void wnorm_kernel(const float* __restrict__ W,
                                                    float* __restrict__ rnw, int N) {
  const int d = blockIdx.x;
  const float2* row2 = (const float2*)(W + (size_t)d * N);
  const int n2 = N >> 1;
  float s = 0.f;
  for (int i = threadIdx.x; i < n2; i += 256) {
    const float2 v = row2[i];
    s += v.x * v.x + v.y * v.y;
  }
  if (threadIdx.x == 0 && (N & 1)) {
    const float v = W[(size_t)d * N + (N - 1)];
    s += v * v;
  }
#pragma unroll
  for (int off = 32; off > 0; off >>= 1) s += __shfl_xor(s, off);
  __shared__ float red[4];
  if ((threadIdx.x & 63) == 0) red[threadIdx.x >> 6] = s;
  __syncthreads();
  if (threadIdx.x == 0)
    rnw[d] = rsqrtf(fmaxf(red[0] + red[1] + red[2] + red[3], L2EPS));
}

// ---------------------------------------------------------------------------
// Kernel 2 (fused dispatch): blocks [0,nxb): normalize x rows AND fold rnw.
// Blocks [nxb,...): transpose-cast BT[n][d] = bf16(W[d][n]), zero-padded.
// ---------------------------------------------------------------------------
__global__ __launch_bounds__(256) void prep_kernel(const float* __restrict__ x,
                                                   const float* __restrict__ W,
                                                   const float* __restrict__ rnw,
                                                   unsigned short* __restrict__ xb,
                                                   unsigned short* __restrict__ BT,
                                                   int N, int nxb, int nwx) {
  const int bid = blockIdx.x;
  if (bid < nxb) {
    const int lane = threadIdx.x & 63;
    const int wave = threadIdx.x >> 6;
    const int row  = bid * 4 + wave;
    const float4* xr = (const float4*)(x + (size_t)row * 512);
    const float4 v0 = xr[lane * 2];
    const float4 v1 = xr[lane * 2 + 1];
    float s = v0.x*v0.x + v0.y*v0.y + v0.z*v0.z + v0.w*v0.w
            + v1.x*v1.x + v1.y*v1.y + v1.z*v1.z + v1.w*v1.w;
#pragma unroll
    for (int off = 32; off > 0; off >>= 1) s += __shfl_xor(s, off);
    const float r = rsqrtf(fmaxf(s, L2EPS));
    const float4 w0 = ((const float4*)rnw)[lane * 2];
    const float4 w1 = ((const float4*)rnw)[lane * 2 + 1];
    short8 o;
    o[0] = (short)f2bf(v0.x * r * w0.x); o[1] = (short)f2bf(v0.y * r * w0.y);
    o[2] = (short)f2bf(v0.z * r * w0.z); o[3] = (short)f2bf(v0.w * r * w0.w);
    o[4] = (short)f2bf(v1.x * r * w1.x); o[5] = (short)f2bf(v1.y * r * w1.y);
    o[6] = (short)f2bf(v1.z * r * w1.z); o[7] = (short)f2bf(v1.w * r * w1.w);
    *(short8*)(xb + (size_t)row * 512 + lane * 8) = o;
  } else {
    __shared__ unsigned short tile[32][33];
    const int wb = bid - nxb;
    const int n0 = (wb % nwx) * 32;
    const int d0 = (wb / nwx) * 32;
    const int tx = threadIdx.x & 31;
    const int ty = threadIdx.x >> 5;  // 0..7
#pragma unroll
    for (int i = 0; i < 4; ++i) {
      const int dl = ty + i * 8;
      const int n = n0 + tx;
      float v = 0.f;
      if (n < N) v = W[(size_t)(d0 + dl) * N + n];
      tile[tx][dl] = f2bf(v);
    }
    __syncthreads();
#pragma unroll
    for (int i = 0; i < 4; ++i) {
      const int nl = ty + i * 8;
      BT[(size_t)(n0 + nl) * 512 + d0 + tx] = tile[nl][tx];
    }
  }
}

// ---------------------------------------------------------------------------
// Kernel 3: EXACTLY-ONE-PASS GEMM (champion, r16/r20 reproduced 54.5/54.7us).
// Tile 256x384, grid 16x16 = 256 blocks = 1 block/CU, one pass, zero tail:
// each CU pays ONE prologue + 8 drains + ONE epilogue for the entire GEMM.
// 8 waves (2M x 4N, wave = 128x96, acc 8x6 frags). BK=64, double-buffered
// LDS (2 x (A 32KB + B 48KB) = exactly 160KB). Per K-tile: stage next (10
// instrs) -> compute current (96 MFMA/wave) -> vmcnt(0) + one barrier.
// Chunk-XOR swizzle both sides (r3-measured 0 conflicts); source
// pre-swizzled (rule #21). n-inner scalar epilogue (WRITE ~97MB ideal).
// Closed exits (measured): counted-vmcnt needs >2 buffers -> BK shrink
// -> -17us (r18); drain-overlap via tile shrink -> LDS-ratio cliff -> +5us
// (r17); prep resplit -> +1.8us (r19).
// ---------------------------------------------------------------------------
__global__ __launch_bounds__(512, 2) void gemm_kernel(
    const unsigned short* __restrict__ A,   // (4096,512) bf16 (xn * rnw)
    const unsigned short* __restrict__ BT,  // (6144,512) bf16 (W^T, padded)
    float* __restrict__ C,                  // (4096,N) f32
    int N) {
  __shared__ unsigned short As[2][256 * 64];   // 2 x 32 KB
  __shared__ unsigned short Bs[2][384 * 64];   // 2 x 48 KB

  const int tid = threadIdx.x;
  const int l   = tid & 63;
  const int w   = tid >> 6;   // 0..7
  const int wr  = w >> 2;     // 0..1  (M half)
  const int wc  = w & 3;      // 0..3  (N quarter)

  // XCD mapping: 256 blocks = 8 XCDs x 32; XCD c owns a 2bx x 16by strip
  // (B panels 2 x 384KB L2-resident; A via L3).
  const int bid = blockIdx.x;
  const int c   = bid & 7;
  const int i   = bid >> 3;                 // 0..31
  const int bx  = c * 2 + (i >> 4);         // 0..15
  const int by  = i & 15;                   // 0..15
  const int row0 = by * 256;
  const int col0 = bx * 384;

  floatx4 acc[8][6];
#pragma unroll
  for (int m = 0; m < 8; ++m)
#pragma unroll
    for (int n = 0; n < 6; ++n)
      acc[m][n] = (floatx4){0.f, 0.f, 0.f, 0.f};

  // staging: one instr = 512 thr x 16B = 8KB = 64 rows of 128B.
  // A: 4 instrs (256 rows), B: 6 instrs (384 rows). LDS dest linear
  // (tid*16B within instr); SOURCE chunk pre-swizzled:
  // chunk_g = (tid&7) ^ (srow&7); instr row-base is a multiple of 64 so
  // (row&7) == (srow&7) for all instrs.
  const int srow = tid >> 3;                               // 0..63
  const int sch  = ((tid & 7) ^ (srow & 7)) * 8;           // elems
  const unsigned short* Ap = A  + (size_t)(row0 + srow) * 512 + sch;
  const unsigned short* Bp = BT + (size_t)(col0 + srow) * 512 + sch;
  const int lo = tid * 8;                                  // LDS elems

#define STAGE(t_) do { \
    _Pragma("unroll") \
    for (int ii = 0; ii < 4; ++ii) \
      gload_lds16(Ap + (size_t)(ii * 64) * 512 + (t_) * 64, &As[(t_) & 1][ii * 4096 + lo]); \
    _Pragma("unroll") \
    for (int ii = 0; ii < 6; ++ii) \
      gload_lds16(Bp + (size_t)(ii * 64) * 512 + (t_) * 64, &Bs[(t_) & 1][ii * 4096 + lo]); \
  } while (0)

  // frag-read geometry: elem = row*64 + ((ks*4+q4)^(row&7))*8; consecutive
  // 8-lane groups cover 8 distinct 16B bank-groups (0 conflicts, r3-measured).
  const int ln15 = l & 15;
  const int q4   = l >> 4;
  const int e7   = ln15 & 7;
  const int cs0  = ((q4) ^ e7) * 8;
  const int cs1  = ((4 + q4) ^ e7) * 8;
  const int aoff = (wr * 128 + ln15) * 64;  // + m*1024
  const int boff = (wc * 96 + ln15) * 64;   // + n*1024

  // prologue: tile 0 staged, landed, published.
  STAGE(0);
  asm volatile("s_waitcnt vmcnt(0)" ::: "memory");
  __syncthreads();

#pragma unroll
  for (int t = 0; t < 8; ++t) {
    const int b = t & 1;
    if (t + 1 < 8) STAGE(t + 1);   // into other buffer; flies during compute
#pragma unroll
    for (int ks = 0; ks < 2; ++ks) {
      const int cs = ks ? cs1 : cs0;
      short8 af[8], bf[6];
#pragma unroll
      for (int m = 0; m < 8; ++m) af[m] = *(const short8*)&As[b][aoff + m * 1024 + cs];
#pragma unroll
      for (int n = 0; n < 6; ++n) bf[n] = *(const short8*)&Bs[b][boff + n * 1024 + cs];
#pragma unroll
      for (int m = 0; m < 8; ++m)
#pragma unroll
        for (int n = 0; n < 6; ++n)
          acc[m][n] = __builtin_amdgcn_mfma_f32_16x16x32_bf16(af[m], bf[n], acc[m][n], 0, 0, 0);
    }
    if (t + 1 < 8) {
      asm volatile("s_waitcnt vmcnt(0)" ::: "memory");  // tile t+1 landed
      __syncthreads();                                  // publish + reads of buf b done
    }
  }
#undef STAGE

  // epilogue: C/D layout col=lane&15, row=(lane>>4)*4+r; n-inner scalar.
  const int rb = row0 + wr * 128 + q4 * 4;
  const int cb = col0 + wc * 96 + ln15;
#pragma unroll
  for (int m = 0; m < 8; ++m) {
#pragma unroll
    for (int r = 0; r < 4; ++r) {
      const size_t o = (size_t)(rb + m * 16 + r) * N + cb;
#pragma unroll
      for (int n = 0; n < 6; ++n) {
        if (cb + n * 16 < N) C[o + n * 16] = acc[m][n][r];
      }
    }
  }
}

// ---------------------------------------------------------------------------
extern "C" void kernel_launch(void* const* d_in, const int* in_sizes, int n_in,
                              void* d_out, int out_size, void* d_ws, size_t ws_size,
                              hipStream_t stream) {
  const float* x = (const float*)d_in[0];
  const float* W = (const float*)d_in[1];
  float* out = (float*)d_out;

  const int D = 512;
  const int B = in_sizes[0] / D;            // 4096
  const int N = in_sizes[1] / D;            // 5994
  const int Npad = 6144;                    // 16 x 384

  char* ws = (char*)d_ws;
  unsigned short* xb  = (unsigned short*)ws;                          // B*D*2
  unsigned short* BTb = (unsigned short*)(ws + (size_t)B * D * 2);    // Npad*D*2
  float* rnw = (float*)(ws + (size_t)B * D * 2 + (size_t)Npad * D * 2);

  const int nxb = B / 4;           // 1024 xnorm blocks
  const int nwx = Npad / 32;       // 192 wtrans tiles per d-stripe
  const int nwb = nwx * (D / 32);  // 3072 wtrans blocks

  wnorm_kernel<<<D, 256, 0, stream>>>(W, rnw, N);
  prep_kernel<<<nxb + nwb, 256, 0, stream>>>(x, W, rnw, xb, BTb, N, nxb, nwx);
  gemm_kernel<<<(B / 256) * (Npad / 384), 512, 0, stream>>>(xb, BTb, out, N);
}

// Round 22
// 52.121 us; speedup vs baseline: 1.2858x; 1.0495x over previous
//
#include <hip/hip_runtime.h>
#include <hip/hip_bf16.h>

typedef __attribute__((ext_vector_type(8))) short short8;
typedef __attribute__((ext_vector_type(4))) float floatx4;

#define L2EPS 1e-12f

__device__ __forceinline__ unsigned short f2bf(float f) {
  union { float f; unsigned u; } c; c.f = f;
  unsigned u = c.u;
  unsigned r = (u + 0x7fffu + ((u >> 16) & 1u)) >> 16;  // RNE
  return (unsigned short)r;
}

__device__ __forceinline__ void gload_lds16(const void* g, void* l) {
  __builtin_amdgcn_global_load_lds(
      (const __attribute__((address_space(1))) unsigned int*)g,
      (__attribute__((address_space(3))) unsigned int*)l,
      16, 0, 0);
}

// ---------------------------------------------------------------------------
// Kernel 1 (fused, BOTH halves pure functions of W — no cross dependency):
//   blocks [0, D):      wnorm: rnw[d] = rsqrt(max(sum_n W[d,n]^2, eps))
//   blocks [D, D+nwb):  wtrans: BT[n][d] = bf16(W[d][n]), zero-padded
// (rnw folds into A in kernel 2, so wtrans never needed to wait for wnorm;
// the two W-streams run concurrently and L3-amortize the second read.)
// ---------------------------------------------------------------------------
__global__ __launch_bounds__(256) void prepW_kernel(const float* __restrict__ W,
                                                    float* __restrict__ rnw,
                                                    unsigned short* __restrict__ BT,
                                                    int N, int D, int nwx) {
  const int bid = blockIdx.x;
  if (bid < D) {
    const int d = bid;
    const float2* row2 = (const float2*)(W + (size_t)d * N);
    const int n2 = N >> 1;
    float s = 0.f;
    for (int i = threadIdx.x; i < n2; i += 256) {
      const float2 v = row2[i];
      s += v.x * v.x + v.y * v.y;
    }
    if (threadIdx.x == 0 && (N & 1)) {
      const float v = W[(size_t)d * N + (N - 1)];
      s += v * v;
    }
#pragma unroll
    for (int off = 32; off > 0; off >>= 1) s += __shfl_xor(s, off);
    __shared__ float red[4];
    if ((threadIdx.x & 63) == 0) red[threadIdx.x >> 6] = s;
    __syncthreads();
    if (threadIdx.x == 0)
      rnw[d] = rsqrtf(fmaxf(red[0] + red[1] + red[2] + red[3], L2EPS));
  } else {
    __shared__ unsigned short tile[32][33];
    const int wb = bid - D;
    const int n0 = (wb % nwx) * 32;
    const int d0 = (wb / nwx) * 32;
    const int tx = threadIdx.x & 31;
    const int ty = threadIdx.x >> 5;  // 0..7
#pragma unroll
    for (int i = 0; i < 4; ++i) {
      const int dl = ty + i * 8;
      const int n = n0 + tx;
      float v = 0.f;
      if (n < N) v = W[(size_t)(d0 + dl) * N + n];
      tile[tx][dl] = f2bf(v);
    }
    __syncthreads();
#pragma unroll
    for (int i = 0; i < 4; ++i) {
      const int nl = ty + i * 8;
      BT[(size_t)(n0 + nl) * 512 + d0 + tx] = tile[nl][tx];
    }
  }
}

// ---------------------------------------------------------------------------
// Kernel 2: xnorm with rnw fold (champion's prep xnorm half, unchanged):
// xb[row] = bf16(x[row] * rsqrt(sum x^2) * rnw). One wave per row.
// ---------------------------------------------------------------------------
__global__ __launch_bounds__(256) void xnorm_kernel(const float* __restrict__ x,
                                                    const float* __restrict__ rnw,
                                                    unsigned short* __restrict__ xb) {
  const int lane = threadIdx.x & 63;
  const int wave = threadIdx.x >> 6;
  const int row  = blockIdx.x * 4 + wave;
  const float4* xr = (const float4*)(x + (size_t)row * 512);
  const float4 v0 = xr[lane * 2];
  const float4 v1 = xr[lane * 2 + 1];
  float s = v0.x*v0.x + v0.y*v0.y + v0.z*v0.z + v0.w*v0.w
          + v1.x*v1.x + v1.y*v1.y + v1.z*v1.z + v1.w*v1.w;
#pragma unroll
  for (int off = 32; off > 0; off >>= 1) s += __shfl_xor(s, off);
  const float r = rsqrtf(fmaxf(s, L2EPS));
  const float4 w0 = ((const float4*)rnw)[lane * 2];
  const float4 w1 = ((const float4*)rnw)[lane * 2 + 1];
  short8 o;
  o[0] = (short)f2bf(v0.x * r * w0.x); o[1] = (short)f2bf(v0.y * r * w0.y);
  o[2] = (short)f2bf(v0.z * r * w0.z); o[3] = (short)f2bf(v0.w * r * w0.w);
  o[4] = (short)f2bf(v1.x * r * w1.x); o[5] = (short)f2bf(v1.y * r * w1.y);
  o[6] = (short)f2bf(v1.z * r * w1.z); o[7] = (short)f2bf(v1.w * r * w1.w);
  *(short8*)(xb + (size_t)row * 512 + lane * 8) = o;
}

// ---------------------------------------------------------------------------
// Kernel 3: EXACTLY-ONE-PASS GEMM (champion, byte-identical; 54.5/54.7/54.7).
// Tile 256x384, grid 16x16 = 256 blocks = 1 block/CU, one pass, zero tail.
// 8 waves (2M x 4N, wave = 128x96, acc 8x6). BK=64, double-buffered LDS
// (2 x (A 32KB + B 48KB) = exactly 160KB). Per K-tile: stage next (10
// instrs) -> compute (96 MFMA/wave) -> vmcnt(0) + one barrier. Chunk-XOR
// swizzle both sides (0 conflicts); source pre-swizzled (rule #21).
// n-inner scalar epilogue (WRITE ~97MB ideal).
// ---------------------------------------------------------------------------
__global__ __launch_bounds__(512, 2) void gemm_kernel(
    const unsigned short* __restrict__ A,   // (4096,512) bf16 (xn * rnw)
    const unsigned short* __restrict__ BT,  // (6144,512) bf16 (W^T, padded)
    float* __restrict__ C,                  // (4096,N) f32
    int N) {
  __shared__ unsigned short As[2][256 * 64];   // 2 x 32 KB
  __shared__ unsigned short Bs[2][384 * 64];   // 2 x 48 KB

  const int tid = threadIdx.x;
  const int l   = tid & 63;
  const int w   = tid >> 6;   // 0..7
  const int wr  = w >> 2;     // 0..1  (M half)
  const int wc  = w & 3;      // 0..3  (N quarter)

  // XCD mapping: 256 blocks = 8 XCDs x 32; XCD c owns a 2bx x 16by strip.
  const int bid = blockIdx.x;
  const int c   = bid & 7;
  const int i   = bid >> 3;                 // 0..31
  const int bx  = c * 2 + (i >> 4);         // 0..15
  const int by  = i & 15;                   // 0..15
  const int row0 = by * 256;
  const int col0 = bx * 384;

  floatx4 acc[8][6];
#pragma unroll
  for (int m = 0; m < 8; ++m)
#pragma unroll
    for (int n = 0; n < 6; ++n)
      acc[m][n] = (floatx4){0.f, 0.f, 0.f, 0.f};

  // staging: one instr = 512 thr x 16B = 8KB = 64 rows of 128B.
  // A: 4 instrs, B: 6 instrs. LDS dest linear; SOURCE chunk pre-swizzled:
  // chunk_g = (tid&7) ^ (srow&7) (instr row-bases are multiples of 64).
  const int srow = tid >> 3;                               // 0..63
  const int sch  = ((tid & 7) ^ (srow & 7)) * 8;           // elems
  const unsigned short* Ap = A  + (size_t)(row0 + srow) * 512 + sch;
  const unsigned short* Bp = BT + (size_t)(col0 + srow) * 512 + sch;
  const int lo = tid * 8;                                  // LDS elems

#define STAGE(t_) do { \
    _Pragma("unroll") \
    for (int ii = 0; ii < 4; ++ii) \
      gload_lds16(Ap + (size_t)(ii * 64) * 512 + (t_) * 64, &As[(t_) & 1][ii * 4096 + lo]); \
    _Pragma("unroll") \
    for (int ii = 0; ii < 6; ++ii) \
      gload_lds16(Bp + (size_t)(ii * 64) * 512 + (t_) * 64, &Bs[(t_) & 1][ii * 4096 + lo]); \
  } while (0)

  // frag-read geometry: elem = row*64 + ((ks*4+q4)^(row&7))*8; consecutive
  // 8-lane groups cover 8 distinct 16B bank-groups (0 conflicts, r3-measured).
  const int ln15 = l & 15;
  const int q4   = l >> 4;
  const int e7   = ln15 & 7;
  const int cs0  = ((q4) ^ e7) * 8;
  const int cs1  = ((4 + q4) ^ e7) * 8;
  const int aoff = (wr * 128 + ln15) * 64;  // + m*1024
  const int boff = (wc * 96 + ln15) * 64;   // + n*1024

  // prologue: tile 0 staged, landed, published.
  STAGE(0);
  asm volatile("s_waitcnt vmcnt(0)" ::: "memory");
  __syncthreads();

#pragma unroll
  for (int t = 0; t < 8; ++t) {
    const int b = t & 1;
    if (t + 1 < 8) STAGE(t + 1);   // into other buffer; flies during compute
#pragma unroll
    for (int ks = 0; ks < 2; ++ks) {
      const int cs = ks ? cs1 : cs0;
      short8 af[8], bf[6];
#pragma unroll
      for (int m = 0; m < 8; ++m) af[m] = *(const short8*)&As[b][aoff + m * 1024 + cs];
#pragma unroll
      for (int n = 0; n < 6; ++n) bf[n] = *(const short8*)&Bs[b][boff + n * 1024 + cs];
#pragma unroll
      for (int m = 0; m < 8; ++m)
#pragma unroll
        for (int n = 0; n < 6; ++n)
          acc[m][n] = __builtin_amdgcn_mfma_f32_16x16x32_bf16(af[m], bf[n], acc[m][n], 0, 0, 0);
    }
    if (t + 1 < 8) {
      asm volatile("s_waitcnt vmcnt(0)" ::: "memory");  // tile t+1 landed
      __syncthreads();                                  // publish + reads of buf b done
    }
  }
#undef STAGE

  // epilogue: C/D layout col=lane&15, row=(lane>>4)*4+r; n-inner scalar.
  const int rb = row0 + wr * 128 + q4 * 4;
  const int cb = col0 + wc * 96 + ln15;
#pragma unroll
  for (int m = 0; m < 8; ++m) {
#pragma unroll
    for (int r = 0; r < 4; ++r) {
      const size_t o = (size_t)(rb + m * 16 + r) * N + cb;
#pragma unroll
      for (int n = 0; n < 6; ++n) {
        if (cb + n * 16 < N) C[o + n * 16] = acc[m][n][r];
      }
    }
  }
}

// ---------------------------------------------------------------------------
extern "C" void kernel_launch(void* const* d_in, const int* in_sizes, int n_in,
                              void* d_out, int out_size, void* d_ws, size_t ws_size,
                              hipStream_t stream) {
  const float* x = (const float*)d_in[0];
  const float* W = (const float*)d_in[1];
  float* out = (float*)d_out;

  const int D = 512;
  const int B = in_sizes[0] / D;            // 4096
  const int N = in_sizes[1] / D;            // 5994
  const int Npad = 6144;                    // 16 x 384

  char* ws = (char*)d_ws;
  unsigned short* xb  = (unsigned short*)ws;                          // B*D*2
  unsigned short* BTb = (unsigned short*)(ws + (size_t)B * D * 2);    // Npad*D*2
  float* rnw = (float*)(ws + (size_t)B * D * 2 + (size_t)Npad * D * 2);

  const int nwx = Npad / 32;       // 192 wtrans tiles per d-stripe
  const int nwb = nwx * (D / 32);  // 3072 wtrans blocks

  prepW_kernel<<<D + nwb, 256, 0, stream>>>(W, rnw, BTb, N, D, nwx);
  xnorm_kernel<<<B / 4, 256, 0, stream>>>(x, rnw, xb);
  gemm_kernel<<<(B / 256) * (Npad / 384), 512, 0, stream>>>(xb, BTb, out, N);
}